// Round 9
// baseline (572.215 us; speedup 1.0000x reference)
//
#include <hip/hip_runtime.h>
#include <hip/hip_fp16.h>
#include <cstdint>
#include <cstddef>

typedef _Float16 f16x8 __attribute__((ext_vector_type(8)));
typedef _Float16 f16x4 __attribute__((ext_vector_type(4)));
typedef float    f32x4 __attribute__((ext_vector_type(4)));

// ---------------------------------------------------------------------------
// fake-quant with fractional bit-width interpolation (matches jax reference)
// ---------------------------------------------------------------------------
__device__ __forceinline__ float quant_interp(float v, float alpha) {
    float a    = fmaxf(alpha, 1.0f);
    float blo  = floorf(a);
    float frac = a - blo;
    float slo  = exp2f(blo) - 1.0f;
    float shi  = 2.0f * slo + 1.0f;
    float rslo = __builtin_amdgcn_rcpf(slo);
    float rshi = __builtin_amdgcn_rcpf(shi);
    float c    = fminf(fmaxf(v, -1.0f), 1.0f);
    float qlo  = rintf(c * slo) * rslo;
    float qhi  = rintf(c * shi) * rshi;
    return qlo + frac * (qhi - qlo);
}

// ---------------------------------------------------------------------------
// column mean of alpha_a [OUT][IN] -> a_feat [IN], deterministic two-pass
// ---------------------------------------------------------------------------
__global__ void colsum_partial_kernel(const float* __restrict__ aA,
                                      float* __restrict__ partial,
                                      int IN, int rows_per) {
    int col = blockIdx.x * blockDim.x + threadIdx.x;
    size_t r0 = (size_t)blockIdx.y * rows_per;
    float s = 0.f;
    for (int r = 0; r < rows_per; ++r)
        s += aA[(r0 + r) * (size_t)IN + col];
    partial[(size_t)blockIdx.y * IN + col] = s;
}

__global__ void colsum_final_kernel(const float* __restrict__ partial,
                                    float* __restrict__ afeat,
                                    int IN, int nchunk, float inv) {
    int col = blockIdx.x * blockDim.x + threadIdx.x;
    float s = 0.f;
    for (int c = 0; c < nchunk; ++c)
        s += partial[(size_t)c * IN + col];
    afeat[col] = s * inv;
}

// ---------------------------------------------------------------------------
// quantize x [M][K] -> qx in MFMA-FRAGMENT-TILED layout:
//   group index i enumerates (m16, k32, hi, r):  i = ((m16*K32 + k32)*4+hi)*16+r
//   group i holds halfs A[m16*16+r][k32*32 + hi*8 .. +8]  (16B, lane order)
// GEMM loads af[mf][ks] as ONE coalesced dwordx4 (64 lanes x 16B contiguous).
// ---------------------------------------------------------------------------
__global__ void quant_x_tiled_kernel(const float* __restrict__ x,
                                     const float* __restrict__ afeat,
                                     f16x8* __restrict__ qx,
                                     int K, unsigned ngroups) {
    const int K32 = K >> 5;
    unsigned i = blockIdx.x * blockDim.x + threadIdx.x;
    const unsigned stride = gridDim.x * blockDim.x;
    for (; i < ngroups; i += stride) {
        const int r   = i & 15;
        const int hi  = (i >> 4) & 3;
        const unsigned rest = i >> 6;
        const int k32 = (int)(rest % (unsigned)K32);
        const unsigned m16 = rest / (unsigned)K32;
        const size_t row = (size_t)m16 * 16 + r;
        const int kb = k32 * 32 + hi * 8;
        const float* xp = x + row * K + kb;
        f32x4 x0 = *(const f32x4*)xp;
        f32x4 x1 = *(const f32x4*)(xp + 4);
        f32x4 a0 = *(const f32x4*)(afeat + kb);
        f32x4 a1 = *(const f32x4*)(afeat + kb + 4);
        f16x8 o;
        #pragma unroll
        for (int j = 0; j < 4; ++j) o[j]     = (_Float16)quant_interp(x0[j], a0[j]);
        #pragma unroll
        for (int j = 0; j < 4; ++j) o[4 + j] = (_Float16)quant_interp(x1[j], a1[j]);
        qx[i] = o;
    }
}

__global__ void quant_w_kernel(const float* __restrict__ w,
                               const float* __restrict__ aw,
                               f16x4* __restrict__ qw, size_t n4) {
    size_t i = (size_t)blockIdx.x * blockDim.x + threadIdx.x;
    size_t stride = (size_t)gridDim.x * blockDim.x;
    for (; i < n4; i += stride) {
        f32x4 wv = *(const f32x4*)(w + i * 4);
        f32x4 av = *(const f32x4*)(aw + i * 4);
        f16x4 o;
        #pragma unroll
        for (int j = 0; j < 4; ++j) o[j] = (_Float16)quant_interp(wv[j], av[j]);
        qw[i] = o;
    }
}

// ---------------------------------------------------------------------------
// 256x256 NT GEMM, fp16 in / fp32 out. "A-TILED-DIRECT v2":
//   R8 failed via vmcnt FIFO POISONING: af-mh1 loads were issued AFTER the
//   B-stage, so MFMA cluster-1's wait degenerated to vmcnt(0) -> mid-tile
//   drain of B(t+1) staging -> raw HBM latency exposed every tile
//   (7324 cyc/tile vs R6's 4744). Fix: issue order per tile is now
//     [16 af loads][8 bf ds_reads][sched_barrier(0)][4 B-stage loads]
//   FIFO gives counted waits: cluster0 <- vmcnt(12), cluster1 <- vmcnt(4);
//   the stage is only drained at the tile-end GATE0, ~2500 cyc after issue
//   (free). A-dup (4 waves share wm) absorbed by L1/L2/L3 -- R8's FETCH_SIZE
//   proved this (~300MB, unchanged from LDS-A). LDS pipe is B-only:
//   64KB reads + 32KB writes /tile ~= 1000 cyc << 2483 cyc MFMA floor.
//   Sync: ONE vmcnt(0) + ONE barrier per K-tile. No manual pre-MFMA drains.
//   VGPR: acc 128 + af 64 + bf 32 + addr ~= 240 < 256 (2 waves/SIMD).
// ---------------------------------------------------------------------------
__device__ __forceinline__ void gload_lds16(const void* g, void* l) {
    __builtin_amdgcn_global_load_lds(
        (const __attribute__((address_space(1))) void*)g,
        (__attribute__((address_space(3))) void*)l, 16, 0, 0);
}

__device__ __forceinline__ f16x8 lds_frag(const _Float16* buf, int row, int ks, int hi) {
    const int sl = (ks * 4 + hi) ^ (row & 7);
    return *(const f16x8*)((const char*)buf + row * 128 + sl * 16);
}

#define GATE0()  asm volatile("s_waitcnt vmcnt(0)" ::: "memory")
#define BAR()    asm volatile("s_barrier" ::: "memory")

__global__ __launch_bounds__(512, 2) void gemm_atd2_kernel(
    const _Float16* __restrict__ Aq,  // fragment-tiled qx
    const _Float16* __restrict__ B,   // [N][K] qw
    const float* __restrict__ bias,   // [N]
    float* __restrict__ C,            // [M][N]
    int M, int N, int K)
{
    constexpr int BK = 64;
    __shared__ _Float16 sB[2][256 * BK];   // 2 x 32 KiB

    const int tid  = (int)threadIdx.x;
    const int lane = tid & 63;
    const int wave = tid >> 6;
    const int wm   = wave >> 2;    // 0..1
    const int wn   = wave & 3;     // 0..3
    const int r15  = lane & 15;
    const int hi   = lane >> 4;

    const int nbx = N >> 8;
    const int nwg = (M >> 8) * nbx;
    const int bid = (int)blockIdx.x;
    const int swz = (nwg & 7) ? bid : ((bid & 7) * (nwg >> 3) + (bid >> 3));
    const size_t bm0 = (size_t)(swz / nbx) << 8;
    const size_t bn0 = (size_t)(swz % nbx) << 8;

    const int nkt = K / BK;
    const int K32 = K >> 5;
    const _Float16* Bgb = B + bn0 * K;
    // A fragment-chunk (m16, c) lives at (m16*K32 + c)*512 halfs; lane
    // offset = lane*8. Frag mf covers rows (mf>>2)*128 + wm*64 + (mf&3)*16
    //   -> m16 = (mf>>2)*8 + wm*4 + (mf&3)
    const _Float16* Alane = Aq + (size_t)lane * 8;
    const size_t m16b = (bm0 >> 4);

    // stage B tile (256 rows x 64 halfs = 32KB): 4 gload_lds per thread-block
    auto STAGE_B = [&](int tile) {
        if (tile >= nkt) return;
        const _Float16* g = Bgb + (size_t)tile * BK;
        _Float16* lb = sB[tile & 1];
        #pragma unroll
        for (int rr = 0; rr < 4; ++rr) {
            const int row = rr * 64 + (tid >> 3);
            const int sg  = (tid & 7) ^ (row & 7);
            gload_lds16(g + (size_t)row * K + sg * 8,
                        (char*)lb + ((rr * 64) << 7) + (wave << 10));
        }
    };

    f32x4 acc[8][4] = {};
    f16x8 af[8][2], bf[4][2];

    // prologue: stage tile0's B; one-time drain
    STAGE_B(0);
    GATE0(); BAR();

    for (int t = 0; t < nkt; ++t) {
        const _Float16* Bb = sB[t & 1];

        // ALL 16 A fragment loads first (oldest in the vm FIFO)
        #pragma unroll
        for (int mf = 0; mf < 8; ++mf) {
            const size_t m16 = m16b + (size_t)((mf >> 2) * 8 + wm * 4 + (mf & 3));
            #pragma unroll
            for (int ks = 0; ks < 2; ++ks)
                af[mf][ks] = *(const f16x8*)(Alane +
                             ((m16 * K32 + (size_t)(t * 2 + ks)) << 9));
        }
        // B fragments (8 x ds_read_b128, register-resident for whole tile)
        #pragma unroll
        for (int nf = 0; nf < 4; ++nf) {
            const int row = (nf >> 1) * 128 + wn * 32 + (nf & 1) * 16 + r15;
            bf[nf][0] = lds_frag(Bb, row, 0, hi);
            bf[nf][1] = lds_frag(Bb, row, 1, hi);
        }
        // pin: stage must stay NEWEST in the vm FIFO (no hoist above reads)
        __builtin_amdgcn_sched_barrier(0);
        STAGE_B(t + 1);

        // cluster 0 (af[0..3]): compiler wait = counted vmcnt(12)
        __builtin_amdgcn_s_setprio(1);
        #pragma unroll
        for (int mi = 0; mi < 4; ++mi)
            #pragma unroll
            for (int nf = 0; nf < 4; ++nf) {
                f32x4& ac = acc[mi][nf];
                ac = __builtin_amdgcn_mfma_f32_16x16x32_f16(af[mi][0], bf[nf][0], ac, 0, 0, 0);
                ac = __builtin_amdgcn_mfma_f32_16x16x32_f16(af[mi][1], bf[nf][1], ac, 0, 0, 0);
            }
        __builtin_amdgcn_s_setprio(0);

        // cluster 1 (af[4..7]): compiler wait = counted vmcnt(4)
        __builtin_amdgcn_s_setprio(1);
        #pragma unroll
        for (int mi = 0; mi < 4; ++mi)
            #pragma unroll
            for (int nf = 0; nf < 4; ++nf) {
                f32x4& ac = acc[4 + mi][nf];
                ac = __builtin_amdgcn_mfma_f32_16x16x32_f16(af[4 + mi][0], bf[nf][0], ac, 0, 0, 0);
                ac = __builtin_amdgcn_mfma_f32_16x16x32_f16(af[4 + mi][1], bf[nf][1], ac, 0, 0, 0);
            }
        __builtin_amdgcn_s_setprio(0);

        // tile boundary: stage issued ~2500 cyc ago -> near-free drain
        GATE0(); BAR();
    }

    // epilogue: C/D layout col = lane&15, row = (lane>>4)*4 + reg
    #pragma unroll
    for (int nf = 0; nf < 4; ++nf) {
        const size_t col = bn0 + (size_t)((nf >> 1) * 128 + wn * 32 + (nf & 1) * 16 + r15);
        const float bv = bias[col];
        #pragma unroll
        for (int mf = 0; mf < 8; ++mf) {
            const size_t row0 = bm0 + (size_t)((mf >> 2) * 128 + wm * 64 + (mf & 3) * 16 + hi * 4);
            #pragma unroll
            for (int r = 0; r < 4; ++r)
                C[(row0 + r) * N + col] = acc[mf][nf][r] + bv;
        }
    }
}

// ---------------------------------------------------------------------------
extern "C" void kernel_launch(void* const* d_in, const int* in_sizes, int n_in,
                              void* d_out, int out_size, void* d_ws, size_t ws_size,
                              hipStream_t stream) {
    const float* x    = (const float*)d_in[0];
    const float* w    = (const float*)d_in[1];
    const float* bias = (const float*)d_in[2];
    const float* aw   = (const float*)d_in[3];
    const float* aA   = (const float*)d_in[4];

    const int    OUT = in_sizes[2];
    const size_t wsz = (size_t)in_sizes[1];
    const int    IN  = (int)(wsz / OUT);
    const int    M   = in_sizes[0] / IN;    // 8192
    const int    N   = OUT;                 // 4096
    const int    K   = IN;                  // 4096

    char* ws = (char*)d_ws;
    _Float16* qx = (_Float16*)ws;                                   // M*K*2 (tiled)
    _Float16* qw = (_Float16*)(ws + (size_t)M * K * 2);             // N*K*2
    float* afeat   = (float*)(ws + (size_t)M * K * 2 + (size_t)N * K * 2);
    float* partial = afeat + K;                                     // 32*K

    const int NCHUNK = 32;
    dim3 g1(K / 256, NCHUNK);
    colsum_partial_kernel<<<g1, 256, 0, stream>>>(aA, partial, K, OUT / NCHUNK);
    colsum_final_kernel<<<K / 256, 256, 0, stream>>>(partial, afeat, K, NCHUNK,
                                                     1.0f / (float)OUT);

    const unsigned ngroups = (unsigned)((size_t)M * K / 8);
    quant_x_tiled_kernel<<<2048, 256, 0, stream>>>(x, afeat, (f16x8*)qx, K,
                                                   ngroups);
    quant_w_kernel<<<2048, 256, 0, stream>>>(w, aw, (f16x4*)qw,
                                             (size_t)N * K / 4);

    const int nwg = (M / 256) * (N / 256);
    gemm_atd2_kernel<<<nwg, 512, 0, stream>>>(qx, qw, bias, (float*)d_out,
                                              M, N, K);
}

// Round 11
// 477.638 us; speedup vs baseline: 1.1980x; 1.1980x over previous
//
#include <hip/hip_runtime.h>
#include <hip/hip_fp16.h>
#include <cstdint>
#include <cstddef>

typedef _Float16 f16x8 __attribute__((ext_vector_type(8)));
typedef _Float16 f16x4 __attribute__((ext_vector_type(4)));
typedef float    f32x4 __attribute__((ext_vector_type(4)));

// ---------------------------------------------------------------------------
// fake-quant with fractional bit-width interpolation (matches jax reference)
// ---------------------------------------------------------------------------
__device__ __forceinline__ float quant_interp(float v, float alpha) {
    float a    = fmaxf(alpha, 1.0f);
    float blo  = floorf(a);
    float frac = a - blo;
    float slo  = exp2f(blo) - 1.0f;
    float shi  = 2.0f * slo + 1.0f;
    float rslo = __builtin_amdgcn_rcpf(slo);
    float rshi = __builtin_amdgcn_rcpf(shi);
    float c    = fminf(fmaxf(v, -1.0f), 1.0f);
    float qlo  = rintf(c * slo) * rslo;
    float qhi  = rintf(c * shi) * rshi;
    return qlo + frac * (qhi - qlo);
}

// ---------------------------------------------------------------------------
// column mean of alpha_a [OUT][IN] -> a_feat [IN], deterministic two-pass
// ---------------------------------------------------------------------------
__global__ void colsum_partial_kernel(const float* __restrict__ aA,
                                      float* __restrict__ partial,
                                      int IN, int rows_per) {
    int col = blockIdx.x * blockDim.x + threadIdx.x;
    size_t r0 = (size_t)blockIdx.y * rows_per;
    float s = 0.f;
    for (int r = 0; r < rows_per; ++r)
        s += aA[(r0 + r) * (size_t)IN + col];
    partial[(size_t)blockIdx.y * IN + col] = s;
}

__global__ void colsum_final_kernel(const float* __restrict__ partial,
                                    float* __restrict__ afeat,
                                    int IN, int nchunk, float inv) {
    int col = blockIdx.x * blockDim.x + threadIdx.x;
    float s = 0.f;
    for (int c = 0; c < nchunk; ++c)
        s += partial[(size_t)c * IN + col];
    afeat[col] = s * inv;
}

// ---------------------------------------------------------------------------
// fused quantize: x [M][IN] (per-column alpha) then w [OUT][IN] (per-elem
// alpha), one launch (saves an inter-kernel gap). Grid-stride over both.
// ---------------------------------------------------------------------------
__global__ void quant_xw_kernel(const float* __restrict__ x,
                                const float* __restrict__ afeat,
                                f16x4* __restrict__ qx,
                                const float* __restrict__ w,
                                const float* __restrict__ aw,
                                f16x4* __restrict__ qw,
                                int IN, size_t nx4, size_t ntot4) {
    size_t i = (size_t)blockIdx.x * blockDim.x + threadIdx.x;
    size_t stride = (size_t)gridDim.x * blockDim.x;
    for (; i < ntot4; i += stride) {
        if (i < nx4) {
            size_t e = i * 4;
            int col = (int)(e % (size_t)IN);
            f32x4 xv = *(const f32x4*)(x + e);
            f32x4 av = *(const f32x4*)(afeat + col);
            f16x4 o;
            #pragma unroll
            for (int j = 0; j < 4; ++j) o[j] = (_Float16)quant_interp(xv[j], av[j]);
            qx[i] = o;
        } else {
            size_t k = i - nx4;
            f32x4 wv = *(const f32x4*)(w + k * 4);
            f32x4 av = *(const f32x4*)(aw + k * 4);
            f16x4 o;
            #pragma unroll
            for (int j = 0; j < 4; ++j) o[j] = (_Float16)quant_interp(wv[j], av[j]);
            qw[k] = o;
        }
    }
}

// ---------------------------------------------------------------------------
// 256x256 NT GEMM, fp16 in / fp32 out. R6 skeleton + 4-group k-slice register
// rotation, with a DEEPER drain ledger (mid=vmcnt(6), end=vmcnt(4)) so that:
//   * entering tile T, ALL of tile T's data is landed AND published
//     (end-of-(T-1) gate drained B0/B1/A1(T); A0(T) drained a tile earlier)
//   * the only window pre-read (af2 <- A0(T+1) ks0, after end gate, before
//     end BAR) touches data every wave drained at its MID gate of tile T --
//     published by the mid BAR. (R10's race #2: window reads of B were only
//     gated by MY wave's vmcnt; cross-wave publication = gate + barrier.)
//   * R10's race #1 (reading A1(T) before the gate that lands it) is gone:
//     mh1 groups sit after the mid gate+BAR, and under this ledger A1(T)
//     landed a full tile earlier anyway.
// Flight times: stages land 0.9-1.4 tiles after issue (3500-5500 cyc >> 900
// cyc HBM latency) -> deeper gates add no stall.
// Tile = g0(mh0,ks0: bfA read, af2 preloaded) g1(mh0,ks1: af2 rotate + bfB)
//        | GATE(6) BAR | g2(mh1,ks0: af2) g3(mh1,ks1: af2) | GATE(4) window BAR
// af2 rotation puts a WAR edge between group g's MFMAs and g+1's ds_reads --
// hoisting is bounded to ~1 group, forcing read/MFMA interleave (the R6
// residual: 16 hoisted reads = ~1500 cyc tile-top LDS bubble).
// Stage placement/order byte-identical to R6: g0:B1(T+1) g1:A1(T+1)
// g2:A0(T+2) g3:B0(T+2). Last two tiles gate 0 (stage-skip shrinks queue).
// XOR slot swizzle: phys slot = logical ^ (row&7); inverse applied to the
// GLOBAL source, linear LDS dest (rule #21). 0 bank conflicts (measured).
// ---------------------------------------------------------------------------
__device__ __forceinline__ void gload_lds16(const void* g, void* l) {
    __builtin_amdgcn_global_load_lds(
        (const __attribute__((address_space(1))) void*)g,
        (__attribute__((address_space(3))) void*)l, 16, 0, 0);
}

__device__ __forceinline__ f16x8 lds_frag(const _Float16* buf, int row, int ks, int hi) {
    const int sl = (ks * 4 + hi) ^ (row & 7);
    return *(const f16x8*)((const char*)buf + row * 128 + sl * 16);
}

#define GATE(N)  asm volatile("s_waitcnt vmcnt(" N ")" ::: "memory")
#define BAR()    asm volatile("s_barrier" ::: "memory")

#define READ_A2(BUF, MH, KS)                                                 \
    _Pragma("unroll")                                                        \
    for (int mi = 0; mi < 4; ++mi)                                           \
        af2[mi] = lds_frag(BUF, (MH) * 128 + wm * 64 + mi * 16 + r15, KS, hi);

#define READ_B2(BUF, KS, DST)                                                \
    _Pragma("unroll")                                                        \
    for (int nf = 0; nf < 4; ++nf)                                           \
        DST[nf] = lds_frag(BUF, (nf >> 1) * 128 + wn * 32 + (nf & 1) * 16 + r15, KS, hi);

#define MFMA16(MH, BF)                                                       \
    __builtin_amdgcn_s_setprio(1);                                           \
    _Pragma("unroll")                                                        \
    for (int mi = 0; mi < 4; ++mi)                                           \
        _Pragma("unroll")                                                    \
        for (int nf = 0; nf < 4; ++nf)                                       \
            acc[(MH) * 4 + mi][nf] = __builtin_amdgcn_mfma_f32_16x16x32_f16( \
                af2[mi], BF[nf], acc[(MH) * 4 + mi][nf], 0, 0, 0);           \
    __builtin_amdgcn_s_setprio(0);

// which: 0=A0 1=A1 2=B0 3=B1
#define TILE4(T, G0, G1)                                                     \
  {                                                                          \
    const _Float16* Ab = sA[(T) & 1];                                        \
    const _Float16* Bb = sB[(T) & 1];                                        \
    /* g0 (mh0,ks0): af2 preloaded at prev boundary; bfA read here */        \
    READ_B2(Bb, 0, bfA);                                                     \
    STAGE((T) + 1, 3);                                                       \
    MFMA16(0, bfA);                                                          \
    /* g1 (mh0,ks1): af2 rotates (WAR on g0) */                              \
    READ_A2(Ab, 0, 1);                                                       \
    READ_B2(Bb, 1, bfB);                                                     \
    STAGE((T) + 1, 1);                                                       \
    MFMA16(0, bfB);                                                          \
    GATE(G0); BAR();      /* drains A0(T+1); publishes it at this BAR */     \
    /* g2 (mh1,ks0): all tile-T data landed a tile ago */                    \
    READ_A2(Ab, 1, 0);                                                       \
    STAGE((T) + 2, 0);                                                       \
    MFMA16(1, bfA);                                                          \
    /* g3 (mh1,ks1) */                                                       \
    READ_A2(Ab, 1, 1);                                                       \
    STAGE((T) + 2, 2);                                                       \
    MFMA16(1, bfB);                                                          \
    GATE(G1);             /* drains B0,B1,A1(T+1) */                         \
    if ((T) + 1 < nkt)    /* A0(T+1) ks0: published at this tile's mid BAR */\
        READ_A2(sA[((T) + 1) & 1], 0, 0);                                    \
    BAR();                                                                   \
  }

__global__ __launch_bounds__(512, 2) void gemm_g4_kernel(
    const _Float16* __restrict__ A,   // [M][K] qx
    const _Float16* __restrict__ B,   // [N][K] qw
    const float* __restrict__ bias,   // [N]
    float* __restrict__ C,            // [M][N]
    int M, int N, int K)
{
    constexpr int BK = 64;
    __shared__ _Float16 sA[2][256 * BK];   // 64 KiB
    __shared__ _Float16 sB[2][256 * BK];   // 64 KiB

    const int tid  = (int)threadIdx.x;
    const int lane = tid & 63;
    const int wave = tid >> 6;
    const int wm   = wave >> 2;    // 0..1
    const int wn   = wave & 3;     // 0..3
    const int r15  = lane & 15;
    const int hi   = lane >> 4;

    const int nbx = N >> 8;
    const int nwg = (M >> 8) * nbx;
    const int bid = (int)blockIdx.x;
    const int swz = (nwg & 7) ? bid : ((bid & 7) * (nwg >> 3) + (bid >> 3));
    const size_t bm0 = (size_t)(swz / nbx) << 8;
    const size_t bn0 = (size_t)(swz % nbx) << 8;

    const int nkt = K / BK;
    const _Float16* Agb = A + bm0 * K;
    const _Float16* Bgb = B + bn0 * K;

    // stage one half-tile (128 rows x 64 halfs): which 0=A0 1=A1 2=B0 3=B1
    auto STAGE = [&](int tile, int which) {
        if (tile >= nkt) return;
        const _Float16* g = (which < 2 ? Agb : Bgb) + (size_t)tile * BK;
        _Float16* lb = (which < 2 ? sA[tile & 1] : sB[tile & 1]);
        const int rb = (which & 1) << 7;
        #pragma unroll
        for (int rr = 0; rr < 2; ++rr) {
            const int row = rb + rr * 64 + (tid >> 3);
            const int sg  = (tid & 7) ^ (row & 7);
            gload_lds16(g + (size_t)row * K + sg * 8,
                        (char*)lb + ((rb + rr * 64) << 7) + (wave << 10));
        }
    };

    f32x4 acc[8][4] = {};
    f16x8 af2[4], bfA[4], bfB[4];

    // prologue: A0(0),B0(0),B1(0),A1(0),A0(1),B0(1) = 12 loads.
    // GATE(4) drains ALL of tile 0; BAR publishes it; then preload af2.
    // Entering tile 0 queue = [A0(1),B0(1)] = the steady-state invariant.
    STAGE(0, 0); STAGE(0, 2); STAGE(0, 3); STAGE(0, 1);
    STAGE(1, 0); STAGE(1, 2);
    GATE("4");
    BAR();
    READ_A2(sA[0], 0, 0);

    int t = 0;
    for (; t < nkt - 2; ++t)
        TILE4(t, "6", "4");
    for (; t < nkt; ++t)           // tail: stages skip -> full drains
        TILE4(t, "0", "0");

    // epilogue: C/D layout col = lane&15, row = (lane>>4)*4 + reg
    #pragma unroll
    for (int nf = 0; nf < 4; ++nf) {
        const size_t col = bn0 + (size_t)((nf >> 1) * 128 + wn * 32 + (nf & 1) * 16 + r15);
        const float bv = bias[col];
        #pragma unroll
        for (int mf = 0; mf < 8; ++mf) {
            const size_t row0 = bm0 + (size_t)((mf >> 2) * 128 + wm * 64 + (mf & 3) * 16 + hi * 4);
            #pragma unroll
            for (int r = 0; r < 4; ++r)
                C[(row0 + r) * N + col] = acc[mf][nf][r] + bv;
        }
    }
}

// ---------------------------------------------------------------------------
extern "C" void kernel_launch(void* const* d_in, const int* in_sizes, int n_in,
                              void* d_out, int out_size, void* d_ws, size_t ws_size,
                              hipStream_t stream) {
    const float* x    = (const float*)d_in[0];
    const float* w    = (const float*)d_in[1];
    const float* bias = (const float*)d_in[2];
    const float* aw   = (const float*)d_in[3];
    const float* aA   = (const float*)d_in[4];

    const int    OUT = in_sizes[2];
    const size_t wsz = (size_t)in_sizes[1];
    const int    IN  = (int)(wsz / OUT);
    const int    M   = in_sizes[0] / IN;    // 8192
    const int    N   = OUT;                 // 4096
    const int    K   = IN;                  // 4096

    char* ws = (char*)d_ws;
    _Float16* qx = (_Float16*)ws;                                   // M*K*2
    _Float16* qw = (_Float16*)(ws + (size_t)M * K * 2);             // N*K*2
    float* afeat   = (float*)(ws + (size_t)M * K * 2 + (size_t)N * K * 2);
    float* partial = afeat + K;                                     // 32*K

    const int NCHUNK = 32;
    dim3 g1(K / 256, NCHUNK);
    colsum_partial_kernel<<<g1, 256, 0, stream>>>(aA, partial, K, OUT / NCHUNK);
    colsum_final_kernel<<<K / 256, 256, 0, stream>>>(partial, afeat, K, NCHUNK,
                                                     1.0f / (float)OUT);

    const size_t nx4 = (size_t)M * K / 4;
    const size_t nw4 = (size_t)N * K / 4;
    quant_xw_kernel<<<2048, 256, 0, stream>>>(x, afeat, (f16x4*)qx,
                                              w, aw, (f16x4*)qw,
                                              K, nx4, nx4 + nw4);

    const int nwg = (M / 256) * (N / 256);
    gemm_g4_kernel<<<nwg, 512, 0, stream>>>(qx, qw, bias, (float*)d_out,
                                            M, N, K);
}

// Round 12
// 382.163 us; speedup vs baseline: 1.4973x; 1.2498x over previous
//
#include <hip/hip_runtime.h>
#include <hip/hip_fp16.h>
#include <cstdint>
#include <cstddef>

typedef _Float16 f16x8 __attribute__((ext_vector_type(8)));
typedef _Float16 f16x4 __attribute__((ext_vector_type(4)));
typedef float    f32x4 __attribute__((ext_vector_type(4)));

// ---------------------------------------------------------------------------
// fake-quant with fractional bit-width interpolation (matches jax reference)
// ---------------------------------------------------------------------------
__device__ __forceinline__ float quant_interp(float v, float alpha) {
    float a    = fmaxf(alpha, 1.0f);
    float blo  = floorf(a);
    float frac = a - blo;
    float slo  = exp2f(blo) - 1.0f;
    float shi  = 2.0f * slo + 1.0f;
    float rslo = __builtin_amdgcn_rcpf(slo);
    float rshi = __builtin_amdgcn_rcpf(shi);
    float c    = fminf(fmaxf(v, -1.0f), 1.0f);
    float qlo  = rintf(c * slo) * rslo;
    float qhi  = rintf(c * shi) * rshi;
    return (1.0f - frac) * qlo + frac * qhi;
}

// ---------------------------------------------------------------------------
// column mean of alpha_a [OUT][IN] -> a_feat [IN], deterministic two-pass
// ---------------------------------------------------------------------------
__global__ void colsum_partial_kernel(const float* __restrict__ aA,
                                      float* __restrict__ partial,
                                      int IN, int rows_per) {
    int col = blockIdx.x * blockDim.x + threadIdx.x;
    size_t r0 = (size_t)blockIdx.y * rows_per;
    float s = 0.f;
    for (int r = 0; r < rows_per; ++r)
        s += aA[(r0 + r) * (size_t)IN + col];
    partial[(size_t)blockIdx.y * IN + col] = s;
}

__global__ void colsum_final_kernel(const float* __restrict__ partial,
                                    float* __restrict__ afeat,
                                    int IN, int nchunk, float inv) {
    int col = blockIdx.x * blockDim.x + threadIdx.x;
    float s = 0.f;
    for (int c = 0; c < nchunk; ++c)
        s += partial[(size_t)c * IN + col];
    afeat[col] = s * inv;
}

// ---------------------------------------------------------------------------
// fused quantize (ONE launch): x [M][IN] (per-col alpha) then w [OUT][IN]
// (per-elem alpha). 32B loads / 16B store per thread-iteration (G13).
// Arithmetic identical to R6's quant_interp -> absmax unchanged (0.03125).
// ---------------------------------------------------------------------------
__global__ void quant_xw8_kernel(const float* __restrict__ x,
                                 const float* __restrict__ afeat,
                                 f16x8* __restrict__ qx,
                                 const float* __restrict__ w,
                                 const float* __restrict__ aw,
                                 f16x8* __restrict__ qw,
                                 int IN, size_t nx8, size_t ntot8) {
    size_t i = (size_t)blockIdx.x * blockDim.x + threadIdx.x;
    size_t stride = (size_t)gridDim.x * blockDim.x;
    for (; i < ntot8; i += stride) {
        if (i < nx8) {
            size_t e = i * 8;
            int col = (int)(e % (size_t)IN);
            f32x4 x0 = *(const f32x4*)(x + e);
            f32x4 x1 = *(const f32x4*)(x + e + 4);
            f32x4 a0 = *(const f32x4*)(afeat + col);
            f32x4 a1 = *(const f32x4*)(afeat + col + 4);
            f16x8 o;
            #pragma unroll
            for (int j = 0; j < 4; ++j) o[j]     = (_Float16)quant_interp(x0[j], a0[j]);
            #pragma unroll
            for (int j = 0; j < 4; ++j) o[4 + j] = (_Float16)quant_interp(x1[j], a1[j]);
            qx[i] = o;
        } else {
            size_t k = (i - nx8) * 8;
            f32x4 w0 = *(const f32x4*)(w + k);
            f32x4 w1 = *(const f32x4*)(w + k + 4);
            f32x4 a0 = *(const f32x4*)(aw + k);
            f32x4 a1 = *(const f32x4*)(aw + k + 4);
            f16x8 o;
            #pragma unroll
            for (int j = 0; j < 4; ++j) o[j]     = (_Float16)quant_interp(w0[j], a0[j]);
            #pragma unroll
            for (int j = 0; j < 4; ++j) o[4 + j] = (_Float16)quant_interp(w1[j], a1[j]);
            qw[i - nx8] = o;
        }
    }
}

// ---------------------------------------------------------------------------
// 256x256 NT GEMM, fp16 in / fp32 out — BYTE-EXACT R6 (best measured: 253us,
// MfmaUtil 49%, 0 bank conflicts). 2 phases/K-tile, no lockstep forcers:
// compiler emits counted lgkmcnt per MFMA dep; counted vmcnt gates (8,6)
// before each barrier; stages at distance 1/2; XOR slot swizzle with inverse
// on the GLOBAL source (rule #21). R7-R11's five scheduling/data-path
// variants (A-direct, A-tiled-direct x2, 4-phase lockstep, k-slice rotation)
// all regressed -- this structure is the local optimum for this template.
// ---------------------------------------------------------------------------
__device__ __forceinline__ void gload_lds16(const void* g, void* l) {
    __builtin_amdgcn_global_load_lds(
        (const __attribute__((address_space(1))) void*)g,
        (__attribute__((address_space(3))) void*)l, 16, 0, 0);
}

__device__ __forceinline__ f16x8 lds_frag(const _Float16* buf, int row, int ks, int hi) {
    const int sl = (ks * 4 + hi) ^ (row & 7);
    return *(const f16x8*)((const char*)buf + row * 128 + sl * 16);
}

#define GATE(N)  asm volatile("s_waitcnt vmcnt(" N ")" ::: "memory")
#define BAR()    asm volatile("s_barrier" ::: "memory")

#define READ_A(BUF, MH)                                                      \
    _Pragma("unroll")                                                        \
    for (int mi = 0; mi < 4; ++mi) {                                         \
        const int row = (MH) * 128 + wm * 64 + mi * 16 + r15;                \
        af[mi][0] = lds_frag(BUF, row, 0, hi);                               \
        af[mi][1] = lds_frag(BUF, row, 1, hi);                               \
    }

#define READ_BF(BUF)                                                         \
    _Pragma("unroll")                                                        \
    for (int nf = 0; nf < 4; ++nf) {                                         \
        const int row = (nf >> 1) * 128 + wn * 32 + (nf & 1) * 16 + r15;     \
        bf[nf][0] = lds_frag(BUF, row, 0, hi);                               \
        bf[nf][1] = lds_frag(BUF, row, 1, hi);                               \
    }

#define MFMA32(MH)                                                           \
    __builtin_amdgcn_s_setprio(1);                                           \
    _Pragma("unroll")                                                        \
    for (int mi = 0; mi < 4; ++mi)                                           \
        _Pragma("unroll")                                                    \
        for (int nf = 0; nf < 4; ++nf) {                                     \
            f32x4& ac = acc[(MH) * 4 + mi][nf];                              \
            ac = __builtin_amdgcn_mfma_f32_16x16x32_f16(af[mi][0], bf[nf][0], ac, 0, 0, 0); \
            ac = __builtin_amdgcn_mfma_f32_16x16x32_f16(af[mi][1], bf[nf][1], ac, 0, 0, 0); \
        }                                                                    \
    __builtin_amdgcn_s_setprio(0);

// which: 0=A0 1=A1 2=B0 3=B1
#define TILE2(T, G0, G1)                                                     \
  {                                                                          \
    const _Float16* Ab = sA[(T) & 1];                                        \
    const _Float16* Bb = sB[(T) & 1];                                        \
    f16x8 af[4][2];                                                          \
    READ_A(Ab, 0);                                                           \
    READ_BF(Bb);                                                             \
    STAGE((T) + 1, 3); STAGE((T) + 1, 1);                                    \
    MFMA32(0);                                                               \
    GATE(G0); BAR();                                                         \
    READ_A(Ab, 1);                                                           \
    STAGE((T) + 2, 0); STAGE((T) + 2, 2);                                    \
    MFMA32(1);                                                               \
    GATE(G1); BAR();                                                         \
  }

__global__ __launch_bounds__(512, 2) void gemm2pf_kernel(
    const _Float16* __restrict__ A,   // [M][K] qx
    const _Float16* __restrict__ B,   // [N][K] qw
    const float* __restrict__ bias,   // [N]
    float* __restrict__ C,            // [M][N]
    int M, int N, int K)
{
    constexpr int BK = 64;
    __shared__ _Float16 sA[2][256 * BK];   // 64 KiB
    __shared__ _Float16 sB[2][256 * BK];   // 64 KiB

    const int tid  = (int)threadIdx.x;
    const int lane = tid & 63;
    const int wave = tid >> 6;
    const int wm   = wave >> 2;    // 0..1
    const int wn   = wave & 3;     // 0..3
    const int r15  = lane & 15;
    const int hi   = lane >> 4;

    const int nbx = N >> 8;
    const int nwg = (M >> 8) * nbx;
    const int bid = (int)blockIdx.x;
    const int swz = (nwg & 7) ? bid : ((bid & 7) * (nwg >> 3) + (bid >> 3));
    const size_t bm0 = (size_t)(swz / nbx) << 8;
    const size_t bn0 = (size_t)(swz % nbx) << 8;

    const int nkt = K / BK;
    const _Float16* Agb = A + bm0 * K;
    const _Float16* Bgb = B + bn0 * K;

    auto STAGE = [&](int tile, int which) {
        if (tile >= nkt) return;
        const _Float16* g = (which < 2 ? Agb : Bgb) + (size_t)tile * BK;
        _Float16* lb = (which < 2 ? sA[tile & 1] : sB[tile & 1]);
        const int rb = (which & 1) << 7;
        #pragma unroll
        for (int rr = 0; rr < 2; ++rr) {
            const int row = rb + rr * 64 + (tid >> 3);
            const int sg  = (tid & 7) ^ (row & 7);
            gload_lds16(g + (size_t)row * K + sg * 8,
                        (char*)lb + ((rb + rr * 64) << 7) + (wave << 10));
        }
    };

    f32x4 acc[8][4] = {};
    f16x8 bf[4][2];

    // prologue: A0(0),B0(0),B1(0),A1(0),A0(1),B0(1) = 12 loads;
    // vmcnt(6) drains tile0's A0,B0,B1; leaves [A1(0),A0(1),B0(1)] in flight
    STAGE(0, 0); STAGE(0, 2); STAGE(0, 3); STAGE(0, 1);
    STAGE(1, 0); STAGE(1, 2);
    GATE("6"); BAR();

    int t = 0;
    for (; t < nkt - 3; ++t)
        TILE2(t, "8", "6");
    for (; t < nkt; ++t)           // tail: stages skip -> full drain is safe
        TILE2(t, "0", "0");

    // epilogue: C/D layout col = lane&15, row = (lane>>4)*4 + reg
    #pragma unroll
    for (int nf = 0; nf < 4; ++nf) {
        const size_t col = bn0 + (size_t)((nf >> 1) * 128 + wn * 32 + (nf & 1) * 16 + r15);
        const float bv = bias[col];
        #pragma unroll
        for (int mf = 0; mf < 8; ++mf) {
            const size_t row0 = bm0 + (size_t)((mf >> 2) * 128 + wm * 64 + (mf & 3) * 16 + hi * 4);
            #pragma unroll
            for (int r = 0; r < 4; ++r)
                C[(row0 + r) * N + col] = acc[mf][nf][r] + bv;
        }
    }
}

// ---------------------------------------------------------------------------
extern "C" void kernel_launch(void* const* d_in, const int* in_sizes, int n_in,
                              void* d_out, int out_size, void* d_ws, size_t ws_size,
                              hipStream_t stream) {
    const float* x    = (const float*)d_in[0];
    const float* w    = (const float*)d_in[1];
    const float* bias = (const float*)d_in[2];
    const float* aw   = (const float*)d_in[3];
    const float* aA   = (const float*)d_in[4];

    const int    OUT = in_sizes[2];
    const size_t wsz = (size_t)in_sizes[1];
    const int    IN  = (int)(wsz / OUT);
    const int    M   = in_sizes[0] / IN;    // 8192
    const int    N   = OUT;                 // 4096
    const int    K   = IN;                  // 4096

    char* ws = (char*)d_ws;
    _Float16* qx = (_Float16*)ws;                                   // M*K*2
    _Float16* qw = (_Float16*)(ws + (size_t)M * K * 2);             // N*K*2
    float* afeat   = (float*)(ws + (size_t)M * K * 2 + (size_t)N * K * 2);
    float* partial = afeat + K;                                     // 32*K

    const int NCHUNK = 32;
    dim3 g1(K / 256, NCHUNK);
    colsum_partial_kernel<<<g1, 256, 0, stream>>>(aA, partial, K, OUT / NCHUNK);
    colsum_final_kernel<<<K / 256, 256, 0, stream>>>(partial, afeat, K, NCHUNK,
                                                     1.0f / (float)OUT);

    const size_t nx8 = (size_t)M * K / 8;
    const size_t nw8 = (size_t)N * K / 8;
    quant_xw8_kernel<<<2048, 256, 0, stream>>>(x, afeat, (f16x8*)qx,
                                               w, aw, (f16x8*)qw,
                                               K, nx8, nx8 + nw8);

    const int nwg = (M / 256) * (N / 256);
    gemm2pf_kernel<<<nwg, 512, 0, stream>>>(qx, qw, bias, (float*)d_out,
                                            M, N, K);
}